// Round 1
// baseline (452.546 us; speedup 1.0000x reference)
//
#include <hip/hip_runtime.h>

typedef unsigned short u16;
typedef unsigned int u32;
typedef __attribute__((ext_vector_type(8))) __bf16 bf16x8;
typedef __attribute__((ext_vector_type(4))) float f32x4;

#define BM 128
#define BN 128
#define BK 32
#define LP 40   // LDS row pitch in u16 (32 + 8 pad -> 80B rows, 16B aligned, 2-way banks)

__device__ __forceinline__ u16 f2bf(float x) {
    u32 u = __float_as_uint(x);
    u = (u + 0x7FFFu + ((u >> 16) & 1u)) >> 16;
    return (u16)u;
}
__device__ __forceinline__ float bf2f(u16 h) { return __uint_as_float(((u32)h) << 16); }

// ---------------- weight transpose + split: T[n][k] = W[k][n] as bf16 hi/lo ----------------
__global__ __launch_bounds__(256) void transpose_split_k(const float* __restrict__ W,
                                                         u16* __restrict__ Th,
                                                         u16* __restrict__ Tl, int dim) {
    __shared__ float tile[32][33];
    const int bx = blockIdx.x * 32;  // n block
    const int by = blockIdx.y * 32;  // k block
    const int tx = threadIdx.x & 31, ty = threadIdx.x >> 5;  // ty in 0..7
    for (int i = 0; i < 32; i += 8)
        tile[ty + i][tx] = W[(size_t)(by + ty + i) * dim + bx + tx];
    __syncthreads();
    for (int i = 0; i < 32; i += 8) {
        float x = tile[tx][ty + i];          // = W[by+tx][bx+ty+i]
        u16 h = f2bf(x);
        size_t idx = (size_t)(bx + ty + i) * dim + by + tx;   // T[n][k]
        Th[idx] = h;
        Tl[idx] = f2bf(x - bf2f(h));
    }
}

// ---------------- row softmax, fp32 in, bf16 out in place ----------------
__global__ __launch_bounds__(256) void softmax_k(float* __restrict__ S, int N) {
    float* row = S + (size_t)blockIdx.x * N;
    const int t = threadIdx.x;
    float4 va = ((const float4*)row)[2 * t];
    float4 vb = ((const float4*)row)[2 * t + 1];
    float v[8] = {va.x, va.y, va.z, va.w, vb.x, vb.y, vb.z, vb.w};
    float m = v[0];
#pragma unroll
    for (int i = 1; i < 8; i++) m = fmaxf(m, v[i]);
#pragma unroll
    for (int o = 32; o; o >>= 1) m = fmaxf(m, __shfl_xor(m, o));
    __shared__ float smax[4], ssum[4];
    if ((t & 63) == 0) smax[t >> 6] = m;
    __syncthreads();
    m = fmaxf(fmaxf(smax[0], smax[1]), fmaxf(smax[2], smax[3]));
    float s = 0.f;
#pragma unroll
    for (int i = 0; i < 8; i++) { v[i] = __expf(v[i] - m); s += v[i]; }
#pragma unroll
    for (int o = 32; o; o >>= 1) s += __shfl_xor(s, o);
    if ((t & 63) == 0) ssum[t >> 6] = s;
    __syncthreads();
    s = ssum[0] + ssum[1] + ssum[2] + ssum[3];
    const float inv = 1.0f / s;
    u32 w0 = f2bf(v[0] * inv) | ((u32)f2bf(v[1] * inv) << 16);
    u32 w1 = f2bf(v[2] * inv) | ((u32)f2bf(v[3] * inv) << 16);
    u32 w2 = f2bf(v[4] * inv) | ((u32)f2bf(v[5] * inv) << 16);
    u32 w3 = f2bf(v[6] * inv) | ((u32)f2bf(v[7] * inv) << 16);
    uint4 o4; o4.x = w0; o4.y = w1; o4.z = w2; o4.w = w3;
    ((uint4*)row)[t] = o4;   // after barrier: all row reads done
}

// ---------------- generic 128x128 MFMA GEMM, C = A @ BT^T ----------------
// A: [M][K] (fp32 split on the fly, or prestored bf16 hi/lo). BT: [Nsz][K] bf16 hi/lo.
// SPLIT: 3-term hi/lo MFMA for fp32-accurate product. Epilogue: scale, bias, residual,
// fp32 out, bf16 hi(/lo) out, batched-transposed bf16 out (for V^T).
template <int SPLIT, int AFP32>
__global__ __launch_bounds__(256) void gemm_k(
    const float* __restrict__ Afp, const u16* __restrict__ Ah, const u16* __restrict__ Al,
    long lda, long strideA,
    const u16* __restrict__ BTh, const u16* __restrict__ BTl, long ldb, long strideBT,
    const float* __restrict__ bias, const float* __restrict__ resid, long ldres,
    float scale,
    float* __restrict__ Cf, long ldcf,
    u16* __restrict__ Cbh, u16* __restrict__ Cbl, long ldcb,
    u16* __restrict__ CbT, long ldct, long tRows,
    long strideC, int K) {
    __shared__ u16 AsH[BM * LP];
    __shared__ u16 BsH[BN * LP];
    __shared__ u16 AsL[(SPLIT ? BM : 1) * LP];
    __shared__ u16 BsL[(SPLIT ? BN : 1) * LP];

    const long bz = blockIdx.z;
    if constexpr (AFP32) { if (Afp) Afp += bz * strideA; }
    else { Ah += bz * strideA; if constexpr (SPLIT) Al += bz * strideA; }
    BTh += bz * strideBT;
    if constexpr (SPLIT) BTl += bz * strideBT;
    if (Cf) Cf += bz * strideC;
    if (Cbh) Cbh += bz * strideC;
    if (Cbl) Cbl += bz * strideC;

    const int t = threadIdx.x;
    const int m0 = blockIdx.x * BM;
    const int n0 = blockIdx.y * BN;
    const int w = t >> 6, lane = t & 63;
    const int wr = (w >> 1) * 64, wc = (w & 1) * 64;
    const int l15 = lane & 15, quad = lane >> 4;

    f32x4 acc[4][4];
#pragma unroll
    for (int i = 0; i < 4; i++)
#pragma unroll
        for (int j = 0; j < 4; j++) acc[i][j] = (f32x4){0.f, 0.f, 0.f, 0.f};

    for (int k0 = 0; k0 < K; k0 += BK) {
        // ---- stage A ----
        if constexpr (AFP32) {
            const int row = t >> 3, cg = (t & 7) * 4;
#pragma unroll
            for (int p = 0; p < 4; ++p) {
                const int r = row + p * 32;
                const float4 v = *(const float4*)(Afp + (long)(m0 + r) * lda + k0 + cg);
                float xs[4] = {v.x, v.y, v.z, v.w};
                u16 h[4], l[4];
#pragma unroll
                for (int q = 0; q < 4; ++q) {
                    h[q] = f2bf(xs[q]);
                    l[q] = f2bf(xs[q] - bf2f(h[q]));
                }
                *(u32*)&AsH[r * LP + cg] = h[0] | ((u32)h[1] << 16);
                *(u32*)&AsH[r * LP + cg + 2] = h[2] | ((u32)h[3] << 16);
                if constexpr (SPLIT) {
                    *(u32*)&AsL[r * LP + cg] = l[0] | ((u32)l[1] << 16);
                    *(u32*)&AsL[r * LP + cg + 2] = l[2] | ((u32)l[3] << 16);
                }
            }
        } else {
            const int row = t >> 2, cg = (t & 3) * 8;
#pragma unroll
            for (int p = 0; p < 2; ++p) {
                const int r = row + p * 64;
                *(uint4*)&AsH[r * LP + cg] = *(const uint4*)(Ah + (long)(m0 + r) * lda + k0 + cg);
                if constexpr (SPLIT)
                    *(uint4*)&AsL[r * LP + cg] = *(const uint4*)(Al + (long)(m0 + r) * lda + k0 + cg);
            }
        }
        // ---- stage B ----
        {
            const int row = t >> 2, cg = (t & 3) * 8;
#pragma unroll
            for (int p = 0; p < 2; ++p) {
                const int r = row + p * 64;
                *(uint4*)&BsH[r * LP + cg] = *(const uint4*)(BTh + (long)(n0 + r) * ldb + k0 + cg);
                if constexpr (SPLIT)
                    *(uint4*)&BsL[r * LP + cg] = *(const uint4*)(BTl + (long)(n0 + r) * ldb + k0 + cg);
            }
        }
        __syncthreads();

        bf16x8 aH[4], bH[4], aL[4], bL[4];
#pragma unroll
        for (int i = 0; i < 4; i++) {
            aH[i] = *(const bf16x8*)&AsH[(wr + i * 16 + l15) * LP + quad * 8];
            bH[i] = *(const bf16x8*)&BsH[(wc + i * 16 + l15) * LP + quad * 8];
            if constexpr (SPLIT) {
                aL[i] = *(const bf16x8*)&AsL[(wr + i * 16 + l15) * LP + quad * 8];
                bL[i] = *(const bf16x8*)&BsL[(wc + i * 16 + l15) * LP + quad * 8];
            }
        }
#pragma unroll
        for (int i = 0; i < 4; i++)
#pragma unroll
            for (int j = 0; j < 4; j++) {
                acc[i][j] = __builtin_amdgcn_mfma_f32_16x16x32_bf16(aH[i], bH[j], acc[i][j], 0, 0, 0);
                if constexpr (SPLIT) {
                    acc[i][j] = __builtin_amdgcn_mfma_f32_16x16x32_bf16(aH[i], bL[j], acc[i][j], 0, 0, 0);
                    acc[i][j] = __builtin_amdgcn_mfma_f32_16x16x32_bf16(aL[i], bH[j], acc[i][j], 0, 0, 0);
                }
            }
        __syncthreads();
    }

    // ---- epilogue: C/D layout col=lane&15, row=quad*4+reg (m89/m91 verified) ----
#pragma unroll
    for (int i = 0; i < 4; i++) {
#pragma unroll
        for (int j = 0; j < 4; j++) {
            const int mBase = m0 + wr + i * 16 + quad * 4;
            const int nn = n0 + wc + j * 16 + l15;
            const float bvs = bias ? bias[nn] : 0.f;
#pragma unroll
            for (int r = 0; r < 4; r++) {
                const long row = mBase + r;
                float x = acc[i][j][r] * scale + bvs;
                if (resid) x += resid[row * ldres + nn];
                if (Cf) Cf[row * ldcf + nn] = x;
                if (Cbh) {
                    u16 h = f2bf(x);
                    Cbh[row * ldcb + nn] = h;
                    if (Cbl) Cbl[row * ldcb + nn] = f2bf(x - bf2f(h));
                }
                if (CbT) {
                    // batched transpose: Vt[b][n][q], b=row/tRows, q=row%tRows
                    long b = row / tRows, q = row - b * tRows;
                    CbT[(b * (long)gridDim.y * BN + nn) * ldct + q] = f2bf(x);
                }
            }
        }
    }
}

extern "C" void kernel_launch(void* const* d_in, const int* in_sizes, int n_in,
                              void* d_out, int out_size, void* d_ws, size_t ws_size,
                              hipStream_t stream) {
    const float* query = (const float*)d_in[0];
    const float* kv    = (const float*)d_in[1];
    const float* Wq = (const float*)d_in[2];
    const float* bq = (const float*)d_in[3];
    const float* Wk = (const float*)d_in[4];
    const float* bk = (const float*)d_in[5];
    const float* Wv = (const float*)d_in[6];
    const float* bv = (const float*)d_in[7];
    const float* Wo = (const float*)d_in[8];
    const float* bo = (const float*)d_in[9];
    float* out = (float*)d_out;

    const int B = 4, N = 2048, D = 512;
    const long MD = (long)B * N * D;  // 4,194,304 elements (M=8192 rows x 512)

    char* p = (char*)d_ws;
    auto alloc = [&](size_t bytes) { void* r = (void*)p; p += (bytes + 255) & ~(size_t)255; return r; };
    u16* Qh = (u16*)alloc(MD * 2);
    u16* Ql = (u16*)alloc(MD * 2);
    u16* Kh = (u16*)alloc(MD * 2);
    u16* Kl = (u16*)alloc(MD * 2);
    u16* Vt = (u16*)alloc(MD * 2);      // [B][D][N]
    u16* Oh = (u16*)alloc(MD * 2);
    u16* WqTh = (u16*)alloc((long)D * D * 2);
    u16* WqTl = (u16*)alloc((long)D * D * 2);
    u16* WkTh = (u16*)alloc((long)D * D * 2);
    u16* WkTl = (u16*)alloc((long)D * D * 2);
    u16* WvTh = (u16*)alloc((long)D * D * 2);
    u16* WvTl = (u16*)alloc((long)D * D * 2);
    u16* WoTh = (u16*)alloc((long)D * D * 2);
    u16* WoTl = (u16*)alloc((long)D * D * 2);
    float* S = (float*)alloc((long)B * N * N * 4);   // scores, fp32; P bf16 written in place

    const dim3 blk(256, 1, 1);
    const float SCALE = 22.627416997969522f;  // sqrt(512), multiplied per reference

    // weight prep
    transpose_split_k<<<dim3(16, 16, 1), blk, 0, stream>>>(Wq, WqTh, WqTl, D);
    transpose_split_k<<<dim3(16, 16, 1), blk, 0, stream>>>(Wk, WkTh, WkTl, D);
    transpose_split_k<<<dim3(16, 16, 1), blk, 0, stream>>>(Wv, WvTh, WvTl, D);
    transpose_split_k<<<dim3(16, 16, 1), blk, 0, stream>>>(Wo, WoTh, WoTl, D);

    // Q projection: split MFMA, write Qh/Ql
    gemm_k<1, 1><<<dim3(64, 4, 1), blk, 0, stream>>>(
        query, nullptr, nullptr, D, 0,
        WqTh, WqTl, D, 0,
        bq, nullptr, 0, 1.0f,
        nullptr, 0,
        Qh, Ql, D,
        nullptr, 0, 1,
        0, D);
    // K projection
    gemm_k<1, 1><<<dim3(64, 4, 1), blk, 0, stream>>>(
        kv, nullptr, nullptr, D, 0,
        WkTh, WkTl, D, 0,
        bk, nullptr, 0, 1.0f,
        nullptr, 0,
        Kh, Kl, D,
        nullptr, 0, 1,
        0, D);
    // V projection: write V^T per batch (Vt[b][c][q]), plain bf16 output
    gemm_k<1, 1><<<dim3(64, 4, 1), blk, 0, stream>>>(
        kv, nullptr, nullptr, D, 0,
        WvTh, WvTl, D, 0,
        bv, nullptr, 0, 1.0f,
        nullptr, 0,
        nullptr, nullptr, 0,
        Vt, (long)N, (long)N,
        0, D);
    // S = SCALE * Q @ K^T  (split MFMA -> fp32-accurate scores)
    gemm_k<1, 0><<<dim3(16, 16, 4), blk, 0, stream>>>(
        nullptr, Qh, Ql, D, (long)N * D,
        Kh, Kl, D, (long)N * D,
        nullptr, nullptr, 0, SCALE,
        S, N,
        nullptr, nullptr, 0,
        nullptr, 0, 1,
        (long)N * N, D);
    // softmax rows, bf16 P in place
    softmax_k<<<dim3(B * N, 1, 1), blk, 0, stream>>>(S, N);
    // O = P @ V   (A = bf16 P rows, pitch 2N over the fp32 buffer; BT = Vt)
    gemm_k<0, 0><<<dim3(16, 4, 4), blk, 0, stream>>>(
        nullptr, (const u16*)S, nullptr, 2L * N, (long)N * 2 * N,
        Vt, nullptr, N, (long)D * N,
        nullptr, nullptr, 0, 1.0f,
        nullptr, 0,
        Oh, nullptr, D,
        nullptr, 0, 1,
        (long)N * D, N);
    // out = query + O @ Wo + bo
    gemm_k<0, 0><<<dim3(64, 4, 1), blk, 0, stream>>>(
        nullptr, Oh, nullptr, D, 0,
        WoTh, nullptr, D, 0,
        bo, query, D, 1.0f,
        out, D,
        nullptr, nullptr, 0,
        nullptr, 0, 1,
        0, D);
    (void)in_sizes; (void)n_in; (void)out_size; (void)ws_size;
}

// Round 2
// 381.688 us; speedup vs baseline: 1.1856x; 1.1856x over previous
//
#include <hip/hip_runtime.h>

typedef unsigned short u16;
typedef unsigned int u32;
typedef __attribute__((ext_vector_type(8))) __bf16 bf16x8;
typedef __attribute__((ext_vector_type(4))) float f32x4;

#define BK 32

__device__ __forceinline__ u16 f2bf(float x) {
    u32 u = __float_as_uint(x);
    u = (u + 0x7FFFu + ((u >> 16) & 1u)) >> 16;
    return (u16)u;
}
__device__ __forceinline__ float bf2f(u16 h) { return __uint_as_float(((u32)h) << 16); }

#define GLD16(g, l)                                                                        \
    __builtin_amdgcn_global_load_lds((const __attribute__((address_space(1))) void*)(g),   \
                                     (__attribute__((address_space(3))) void*)(l), 16, 0, 0)

// ---------------- elementwise fp32 -> bf16 hi/lo split ----------------
__global__ __launch_bounds__(256) void split2_k(const float* __restrict__ x,
                                                u16* __restrict__ h, u16* __restrict__ l,
                                                long n4) {
    long i = (long)blockIdx.x * 256 + threadIdx.x;
    if (i >= n4) return;
    float4 v = ((const float4*)x)[i];
    float xs[4] = {v.x, v.y, v.z, v.w};
    u16 hh[4], ll[4];
#pragma unroll
    for (int q = 0; q < 4; ++q) {
        hh[q] = f2bf(xs[q]);
        ll[q] = f2bf(xs[q] - bf2f(hh[q]));
    }
    uint2 ph, pl;
    ph.x = hh[0] | ((u32)hh[1] << 16); ph.y = hh[2] | ((u32)hh[3] << 16);
    pl.x = ll[0] | ((u32)ll[1] << 16); pl.y = ll[2] | ((u32)ll[3] << 16);
    ((uint2*)h)[i] = ph;
    ((uint2*)l)[i] = pl;
}

// ---------------- weight transpose + split: T[n][k] = W[k][n] as bf16 hi/lo ----------------
__global__ __launch_bounds__(256) void transpose_split_k(const float* __restrict__ W,
                                                         u16* __restrict__ Th,
                                                         u16* __restrict__ Tl, int dim) {
    __shared__ float tile[32][33];
    const int bx = blockIdx.x * 32;  // n block
    const int by = blockIdx.y * 32;  // k block
    const int tx = threadIdx.x & 31, ty = threadIdx.x >> 5;
    for (int i = 0; i < 32; i += 8)
        tile[ty + i][tx] = W[(size_t)(by + ty + i) * dim + bx + tx];
    __syncthreads();
    for (int i = 0; i < 32; i += 8) {
        float x = tile[tx][ty + i];
        u16 h = f2bf(x);
        size_t idx = (size_t)(bx + ty + i) * dim + by + tx;
        Th[idx] = h;
        Tl[idx] = f2bf(x - bf2f(h));
    }
}

// ---------------- row softmax, fp32 in, bf16 out in place ----------------
__global__ __launch_bounds__(256) void softmax_k(float* __restrict__ S, int N) {
    float* row = S + (size_t)blockIdx.x * N;
    const int t = threadIdx.x;
    float4 va = ((const float4*)row)[2 * t];
    float4 vb = ((const float4*)row)[2 * t + 1];
    float v[8] = {va.x, va.y, va.z, va.w, vb.x, vb.y, vb.z, vb.w};
    float m = v[0];
#pragma unroll
    for (int i = 1; i < 8; i++) m = fmaxf(m, v[i]);
#pragma unroll
    for (int o = 32; o; o >>= 1) m = fmaxf(m, __shfl_xor(m, o));
    __shared__ float smax[4], ssum[4];
    if ((t & 63) == 0) smax[t >> 6] = m;
    __syncthreads();
    m = fmaxf(fmaxf(smax[0], smax[1]), fmaxf(smax[2], smax[3]));
    float s = 0.f;
#pragma unroll
    for (int i = 0; i < 8; i++) { v[i] = __expf(v[i] - m); s += v[i]; }
#pragma unroll
    for (int o = 32; o; o >>= 1) s += __shfl_xor(s, o);
    if ((t & 63) == 0) ssum[t >> 6] = s;
    __syncthreads();
    s = ssum[0] + ssum[1] + ssum[2] + ssum[3];
    const float inv = 1.0f / s;
    u32 w0 = f2bf(v[0] * inv) | ((u32)f2bf(v[1] * inv) << 16);
    u32 w1 = f2bf(v[2] * inv) | ((u32)f2bf(v[3] * inv) << 16);
    u32 w2 = f2bf(v[4] * inv) | ((u32)f2bf(v[5] * inv) << 16);
    u32 w3 = f2bf(v[6] * inv) | ((u32)f2bf(v[7] * inv) << 16);
    uint4 o4; o4.x = w0; o4.y = w1; o4.z = w2; o4.w = w3;
    ((uint4*)row)[t] = o4;
}

// ---------------- MFMA GEMM, C = A @ BT^T, global_load_lds + XOR-swizzled LDS ----------------
// LDS tile layout: 16B-unit u = r*4 + (c8 ^ ((r>>1)&3))  -> conflict-free b128 frag reads,
// DMA-contiguous staging writes. SPLIT: 3-term bf16 hi/lo MFMA for fp32-accurate product.
template <int SPLIT, int BMt, int BNt, int WR, int WC>
__global__ __launch_bounds__(256) void gemm_k(
    const u16* __restrict__ Ah, const u16* __restrict__ Al, long lda, long strideA,
    const u16* __restrict__ BTh, const u16* __restrict__ BTl, long ldb, long strideBT,
    const float* __restrict__ bias1, const float* __restrict__ bias2, int nsplit,
    const float* __restrict__ resid, long ldres, float scale,
    float* __restrict__ Cf, long ldcf,
    u16* __restrict__ Cbh, u16* __restrict__ Cbl, long ldcb,
    u16* __restrict__ CbT, long tRows, long tChans, long ldct,
    long strideC, int K) {
    static_assert(WR * WC == 4, "4 waves");
    constexpr int MI = BMt / WR / 16;
    constexpr int NJ = BNt / WC / 16;
    constexpr int PA = BMt / 64;
    constexpr int PB = BNt / 64;

    __shared__ u16 AsH[BMt * BK];
    __shared__ u16 BsH[BNt * BK];
    __shared__ u16 AsL[(SPLIT ? BMt : 1) * BK];
    __shared__ u16 BsL[(SPLIT ? BNt : 1) * BK];

    const long bz = blockIdx.z;
    Ah += bz * strideA;
    BTh += bz * strideBT;
    if constexpr (SPLIT) { Al += bz * strideA; BTl += bz * strideBT; }
    if (Cf) Cf += bz * strideC;
    if (Cbh) Cbh += bz * strideC;
    if (Cbl) Cbl += bz * strideC;

    const int t = threadIdx.x;
    const int w = t >> 6, lane = t & 63;
    const int l15 = lane & 15, quad = lane >> 4;
    const int m0 = blockIdx.x * BMt, n0 = blockIdx.y * BNt;
    const int wrow = (w / WC) * (BMt / WR);
    const int wcol = (w % WC) * (BNt / WC);

    // staging addresses (lane slot -> LDS slot is identity; lane FETCHES the swizzled col)
    const u16* gAh[PA]; const u16* gAl[PA]; int lA[PA];
    const u16* gBh[PB]; const u16* gBl[PB]; int lB[PB];
#pragma unroll
    for (int p = 0; p < PA; ++p) {
        int slot = p * 256 + t;
        int r = slot >> 2, c = slot & 3;
        int cg = c ^ ((r >> 1) & 3);
        gAh[p] = Ah + (long)(m0 + r) * lda + cg * 8;
        if constexpr (SPLIT) gAl[p] = Al + (long)(m0 + r) * lda + cg * 8;
        lA[p] = (p * 256 + w * 64) * 8;   // wave-uniform base (u16 idx)
    }
#pragma unroll
    for (int p = 0; p < PB; ++p) {
        int slot = p * 256 + t;
        int r = slot >> 2, c = slot & 3;
        int cg = c ^ ((r >> 1) & 3);
        gBh[p] = BTh + (long)(n0 + r) * ldb + cg * 8;
        if constexpr (SPLIT) gBl[p] = BTl + (long)(n0 + r) * ldb + cg * 8;
        lB[p] = (p * 256 + w * 64) * 8;
    }

    // fragment LDS offsets (u16 idx), constant across k-steps
    int aoff[MI], boff[NJ];
#pragma unroll
    for (int i = 0; i < MI; ++i) {
        int r = wrow + i * 16 + l15;
        aoff[i] = (r * 4 + (quad ^ ((r >> 1) & 3))) * 8;
    }
#pragma unroll
    for (int j = 0; j < NJ; ++j) {
        int r = wcol + j * 16 + l15;
        boff[j] = (r * 4 + (quad ^ ((r >> 1) & 3))) * 8;
    }

    f32x4 acc[MI][NJ];
#pragma unroll
    for (int i = 0; i < MI; i++)
#pragma unroll
        for (int j = 0; j < NJ; j++) acc[i][j] = (f32x4){0.f, 0.f, 0.f, 0.f};

    for (int k0 = 0; k0 < K; k0 += BK) {
#pragma unroll
        for (int p = 0; p < PA; ++p) {
            GLD16(gAh[p], AsH + lA[p]);
            gAh[p] += BK;
            if constexpr (SPLIT) { GLD16(gAl[p], AsL + lA[p]); gAl[p] += BK; }
        }
#pragma unroll
        for (int p = 0; p < PB; ++p) {
            GLD16(gBh[p], BsH + lB[p]);
            gBh[p] += BK;
            if constexpr (SPLIT) { GLD16(gBl[p], BsL + lB[p]); gBl[p] += BK; }
        }
        __syncthreads();

        bf16x8 aH[MI], bH[NJ];
#pragma unroll
        for (int i = 0; i < MI; ++i) aH[i] = *(const bf16x8*)&AsH[aoff[i]];
#pragma unroll
        for (int j = 0; j < NJ; ++j) bH[j] = *(const bf16x8*)&BsH[boff[j]];
        if constexpr (SPLIT) {
            bf16x8 aL[MI], bL[NJ];
#pragma unroll
            for (int i = 0; i < MI; ++i) aL[i] = *(const bf16x8*)&AsL[aoff[i]];
#pragma unroll
            for (int j = 0; j < NJ; ++j) bL[j] = *(const bf16x8*)&BsL[boff[j]];
#pragma unroll
            for (int i = 0; i < MI; ++i)
#pragma unroll
                for (int j = 0; j < NJ; ++j) {
                    acc[i][j] = __builtin_amdgcn_mfma_f32_16x16x32_bf16(aH[i], bH[j], acc[i][j], 0, 0, 0);
                    acc[i][j] = __builtin_amdgcn_mfma_f32_16x16x32_bf16(aH[i], bL[j], acc[i][j], 0, 0, 0);
                    acc[i][j] = __builtin_amdgcn_mfma_f32_16x16x32_bf16(aL[i], bH[j], acc[i][j], 0, 0, 0);
                }
        } else {
#pragma unroll
            for (int i = 0; i < MI; ++i)
#pragma unroll
                for (int j = 0; j < NJ; ++j)
                    acc[i][j] = __builtin_amdgcn_mfma_f32_16x16x32_bf16(aH[i], bH[j], acc[i][j], 0, 0, 0);
        }
        __syncthreads();
    }

    // epilogue: C/D layout col=lane&15, row=quad*4+reg
#pragma unroll
    for (int i = 0; i < MI; ++i) {
#pragma unroll
        for (int j = 0; j < NJ; ++j) {
            const int mBase = m0 + wrow + i * 16 + quad * 4;
            const int nn = n0 + wcol + j * 16 + l15;
            const bool norm = nn < nsplit;
            float bvs;
            if (norm) bvs = bias1 ? bias1[nn] : 0.f;
            else bvs = bias2 ? bias2[nn - nsplit] : 0.f;
#pragma unroll
            for (int r = 0; r < 4; ++r) {
                const long row = mBase + r;
                float x = acc[i][j][r] * scale + bvs;
                if (resid) x += resid[row * ldres + nn];
                if (norm) {
                    if (Cf) Cf[row * ldcf + nn] = x;
                    if (Cbh) {
                        u16 h = f2bf(x);
                        Cbh[row * ldcb + nn] = h;
                        if (Cbl) Cbl[row * ldcb + nn] = f2bf(x - bf2f(h));
                    }
                } else {
                    long b = row / tRows, q = row - b * tRows;
                    CbT[(b * tChans + (nn - nsplit)) * ldct + q] = f2bf(x);
                }
            }
        }
    }
}

extern "C" void kernel_launch(void* const* d_in, const int* in_sizes, int n_in,
                              void* d_out, int out_size, void* d_ws, size_t ws_size,
                              hipStream_t stream) {
    const float* query = (const float*)d_in[0];
    const float* kv    = (const float*)d_in[1];
    const float* Wq = (const float*)d_in[2];
    const float* bq = (const float*)d_in[3];
    const float* Wk = (const float*)d_in[4];
    const float* bk = (const float*)d_in[5];
    const float* Wv = (const float*)d_in[6];
    const float* bv = (const float*)d_in[7];
    const float* Wo = (const float*)d_in[8];
    const float* bo = (const float*)d_in[9];
    float* out = (float*)d_out;

    const int B = 4, N = 2048, D = 512;
    const long MD = (long)B * N * D;  // 4,194,304 (8192 rows x 512)
    const int BIG = 1 << 30;

    char* p = (char*)d_ws;
    auto alloc = [&](size_t bytes) { void* r = (void*)p; p += (bytes + 255) & ~(size_t)255; return r; };
    float* S = (float*)alloc((long)B * N * N * 4);   // 67 MB; fp32 scores, bf16 P in place
    // input hi/lo splits alias the S region (dead before QK writes S)
    u16* QXh = (u16*)S;
    u16* QXl = QXh + MD;
    u16* KVh = QXl + MD;
    u16* KVl = KVh + MD;                              // ends at 33.5 MB < 67 MB
    u16* Qh = (u16*)alloc(MD * 2);
    u16* Ql = (u16*)alloc(MD * 2);
    u16* Kh = (u16*)alloc(MD * 2);
    u16* Kl = (u16*)alloc(MD * 2);
    u16* Vt = (u16*)alloc(MD * 2);                    // [B][D][N]
    u16* Oh = (u16*)alloc(MD * 2);
    u16* WqTh = (u16*)alloc((long)D * D * 2);
    u16* WqTl = (u16*)alloc((long)D * D * 2);
    u16* WkvTh = (u16*)alloc((long)2 * D * D * 2);    // rows 0..511 = WkT, 512..1023 = WvT
    u16* WkvTl = (u16*)alloc((long)2 * D * D * 2);
    u16* WoTh = (u16*)alloc((long)D * D * 2);
    u16* WoTl = (u16*)alloc((long)D * D * 2);

    const dim3 blk(256, 1, 1);
    const float SCALE = 22.627416997969522f;  // sqrt(512), multiplied per reference

    // input splits
    split2_k<<<dim3(4096, 1, 1), blk, 0, stream>>>(query, QXh, QXl, MD / 4);
    split2_k<<<dim3(4096, 1, 1), blk, 0, stream>>>(kv, KVh, KVl, MD / 4);
    // weight prep
    transpose_split_k<<<dim3(16, 16, 1), blk, 0, stream>>>(Wq, WqTh, WqTl, D);
    transpose_split_k<<<dim3(16, 16, 1), blk, 0, stream>>>(Wk, WkvTh, WkvTl, D);
    transpose_split_k<<<dim3(16, 16, 1), blk, 0, stream>>>(Wv, WkvTh + (long)D * D, WkvTl + (long)D * D, D);
    transpose_split_k<<<dim3(16, 16, 1), blk, 0, stream>>>(Wo, WoTh, WoTl, D);

    // Q projection (split): Qh/Ql = query @ Wq + bq
    gemm_k<1, 128, 64, 2, 2><<<dim3(64, 8, 1), blk, 0, stream>>>(
        QXh, QXl, D, 0,
        WqTh, WqTl, D, 0,
        bq, nullptr, BIG,
        nullptr, 0, 1.0f,
        nullptr, 0,
        Qh, Ql, D,
        nullptr, 1, 1, 1,
        0, D);
    // K+V projection (split, fused): cols<512 -> Kh/Kl ; cols>=512 -> Vt transposed
    gemm_k<1, 128, 64, 2, 2><<<dim3(64, 16, 1), blk, 0, stream>>>(
        KVh, KVl, D, 0,
        WkvTh, WkvTl, D, 0,
        bk, bv, D,
        nullptr, 0, 1.0f,
        nullptr, 0,
        Kh, Kl, D,
        Vt, (long)N, (long)D, (long)N,
        0, D);
    // S = SCALE * Q @ K^T (split -> fp32-accurate scores)
    gemm_k<1, 128, 128, 2, 2><<<dim3(16, 16, 4), blk, 0, stream>>>(
        Qh, Ql, D, (long)N * D,
        Kh, Kl, D, (long)N * D,
        nullptr, nullptr, BIG,
        nullptr, 0, SCALE,
        S, N,
        nullptr, nullptr, 0,
        nullptr, 1, 1, 1,
        (long)N * N, D);
    // softmax rows, bf16 P in place
    softmax_k<<<dim3(B * N, 1, 1), blk, 0, stream>>>(S, N);
    // O = P @ V  (A = bf16 P rows at pitch 2N u16; BT = Vt)
    gemm_k<0, 64, 64, 2, 2><<<dim3(32, 8, 4), blk, 0, stream>>>(
        (const u16*)S, nullptr, 2L * N, (long)N * 2 * N,
        Vt, nullptr, N, (long)D * N,
        nullptr, nullptr, BIG,
        nullptr, 0, 1.0f,
        nullptr, 0,
        Oh, nullptr, D,
        nullptr, 1, 1, 1,
        (long)N * D, N);
    // out = query + O @ Wo + bo
    gemm_k<0, 128, 64, 2, 2><<<dim3(64, 8, 1), blk, 0, stream>>>(
        Oh, nullptr, D, 0,
        WoTh, nullptr, D, 0,
        bo, nullptr, BIG,
        query, D, 1.0f,
        out, D,
        nullptr, nullptr, 0,
        nullptr, 1, 1, 1,
        0, D);
    (void)in_sizes; (void)n_in; (void)out_size; (void)ws_size;
}